// Round 8
// baseline (268.791 us; speedup 1.0000x reference)
//
#include <hip/hip_runtime.h>
#include <hip/hip_bf16.h>

#define I_DIM 4096
#define J_DIM 4096
#define NPERM0 10
#define NPERM1 10
#define RROWS 4            // output rows per block
#define FUSED_THREADS 512  // each thread owns 8 consecutive columns

typedef float          f32x4 __attribute__((ext_vector_type(4)));
typedef int            i32x4 __attribute__((ext_vector_type(4)));
typedef unsigned short u16x4 __attribute__((ext_vector_type(4)));
typedef unsigned short u16x8 __attribute__((ext_vector_type(8)));

// XOR-swizzle for 8-byte LDS slots: physical = s ^ ((s>>4)&7).
// Bijective (bits 4-6 XOR into bits 0-2). Phase-A writes (s = 8*c8+k,
// fixed k): 16 consecutive lanes hit 16 distinct low-4 slots -> all 32
// banks exactly 4x per wave = conflict-free b64.
__device__ __forceinline__ int swzB(int s) { return s ^ ((s >> 4) & 7); }

// bf16 -> f32: shift into high half.
__device__ __forceinline__ float bf2f(unsigned short u) {
    return __uint_as_float((unsigned)u << 16);
}
// f32 -> bf16 round-to-nearest-even.
__device__ __forceinline__ unsigned short f2bf(float f) {
    unsigned u = __float_as_uint(f);
    u += 0x7FFFu + ((u >> 16) & 1u);
    return (unsigned short)(u >> 16);
}

// soft mask: clip((xi-gamma)*sigmoid(x)+gamma, 0, 1) with xi=1.1, gamma=-0.1
__device__ __forceinline__ float soft_mask(float x) {
    float s = 1.0f / (1.0f + __expf(-x));
    return fminf(fmaxf(1.2f * s - 0.1f, 0.0f), 1.0f);
}

// Pass 0: sw = bf16(weight * soft_mask(sparse_mask)).
// weight/mask single-use -> NT loads; sw re-read 10x -> cached store.
__global__ __launch_bounds__(256) void sw_kernel(
    const float* __restrict__ w, const float* __restrict__ m,
    unsigned short* __restrict__ swb, int n8) {
    int idx = blockIdx.x * blockDim.x + threadIdx.x;
    if (idx >= n8) return;
    const f32x4* w4 = reinterpret_cast<const f32x4*>(w) + 2 * (size_t)idx;
    const f32x4* m4 = reinterpret_cast<const f32x4*>(m) + 2 * (size_t)idx;
    f32x4 w0 = __builtin_nontemporal_load(w4);
    f32x4 w1 = __builtin_nontemporal_load(w4 + 1);
    f32x4 m0 = __builtin_nontemporal_load(m4);
    f32x4 m1 = __builtin_nontemporal_load(m4 + 1);
    u16x8 o;
#pragma unroll
    for (int k = 0; k < 4; ++k) {
        o[k]     = f2bf(w0[k] * soft_mask(m0[k]));
        o[k + 4] = f2bf(w1[k] * soft_mask(m1[k]));
    }
    reinterpret_cast<u16x8*>(swb)[idx] = o;
}

// Fused pass: per block, RROWS=4 output rows; thread t owns columns 8t..8t+7.
//   Phase A (row-mix): software-pipelined — issue p+1's 4 row-loads while
//     consuming p's (8 u16x8 loads in flight = 32 VGPR + 32 acc ≈ 76 live).
//   Phase B (col-mix): LDS bf16 gathers, indices prefetched one q ahead.
// launch_bounds(512,4): VGPR cap 128 — round 7's (512,8) squeezed VGPR to 32
// and serialized phase-A loads (MLP loss canceled the occupancy gain).
__global__ __launch_bounds__(FUSED_THREADS, 4) void fused_kernel(
    const unsigned short* __restrict__ swb,
    const float* __restrict__ ps0,   // (NPERM0, I)
    const float* __restrict__ ps1,   // (NPERM1, J)
    const int*   __restrict__ perm0, // (NPERM0, I)
    const int*   __restrict__ perm1, // (NPERM1, J)
    float* __restrict__ out) {
    __shared__ u16x4 vlds[J_DIM];    // 32 KiB, [c] -> bf16 (r0,r1,r2,r3)

    const int i0 = blockIdx.x * RROWS;
    const int c8 = threadIdx.x;      // column-octet index, 0..511
    const u16x8* swv = reinterpret_cast<const u16x8*>(swb);

    // ---- Phase A (pipelined) ----
    float acc[RROWS][8];
#pragma unroll
    for (int r = 0; r < RROWS; ++r)
#pragma unroll
        for (int k = 0; k < 8; ++k) acc[r][k] = 0.f;

    u16x8 cur[RROWS];
#pragma unroll
    for (int r = 0; r < RROWS; ++r) {
        int row = perm0[i0 + r];                       // p = 0
        cur[r] = swv[(size_t)row * (J_DIM / 8) + c8];
    }
#pragma unroll
    for (int p = 0; p < NPERM0; ++p) {
        u16x8 nxt[RROWS];
        if (p + 1 < NPERM0) {
#pragma unroll
            for (int r = 0; r < RROWS; ++r) {
                int row = perm0[(p + 1) * I_DIM + i0 + r];  // block-uniform
                nxt[r] = swv[(size_t)row * (J_DIM / 8) + c8];
            }
        }
#pragma unroll
        for (int r = 0; r < RROWS; ++r) {
            float s = ps0[p * I_DIM + i0 + r];              // block-uniform
#pragma unroll
            for (int k = 0; k < 8; ++k) acc[r][k] += s * bf2f(cur[r][k]);
        }
        if (p + 1 < NPERM0) {
#pragma unroll
            for (int r = 0; r < RROWS; ++r) cur[r] = nxt[r];
        }
    }
    // Transpose to [c][r] as bf16; swizzled, conflict-free b64 stores.
#pragma unroll
    for (int k = 0; k < 8; ++k) {
        u16x4 t;
#pragma unroll
        for (int r = 0; r < RROWS; ++r) t[r] = f2bf(acc[r][k]);
        vlds[swzB(8 * c8 + k)] = t;
    }
    __syncthreads();

    // ---- Phase B (indices prefetched one q ahead) ----
    float o[RROWS][8];
#pragma unroll
    for (int r = 0; r < RROWS; ++r)
#pragma unroll
        for (int k = 0; k < 8; ++k) o[r][k] = 0.f;

    i32x4 pc0, pc1;
    f32x4 s0, s1;
    {
        const i32x4* pq = reinterpret_cast<const i32x4*>(perm1);
        const f32x4* sq = reinterpret_cast<const f32x4*>(ps1);
        pc0 = pq[2 * c8]; pc1 = pq[2 * c8 + 1];
        s0  = sq[2 * c8]; s1  = sq[2 * c8 + 1];
    }
#pragma unroll
    for (int q = 0; q < NPERM1; ++q) {
        i32x4 npc0, npc1;
        f32x4 ns0, ns1;
        if (q + 1 < NPERM1) {
            const i32x4* pq = reinterpret_cast<const i32x4*>(perm1 + (size_t)(q + 1) * J_DIM);
            const f32x4* sq = reinterpret_cast<const f32x4*>(ps1  + (size_t)(q + 1) * J_DIM);
            npc0 = pq[2 * c8]; npc1 = pq[2 * c8 + 1];
            ns0  = sq[2 * c8]; ns1  = sq[2 * c8 + 1];
        }
        u16x4 g[8];
#pragma unroll
        for (int k = 0; k < 4; ++k) {
            g[k]     = vlds[swzB(pc0[k])];
            g[k + 4] = vlds[swzB(pc1[k])];
        }
#pragma unroll
        for (int k = 0; k < 4; ++k) {
#pragma unroll
            for (int r = 0; r < RROWS; ++r) {
                o[r][k]     += s0[k] * bf2f(g[k][r]);
                o[r][k + 4] += s1[k] * bf2f(g[k + 4][r]);
            }
        }
        if (q + 1 < NPERM1) {
            pc0 = npc0; pc1 = npc1; s0 = ns0; s1 = ns1;
        }
    }
#pragma unroll
    for (int r = 0; r < RROWS; ++r) {
        f32x4 t0, t1;
#pragma unroll
        for (int k = 0; k < 4; ++k) { t0[k] = o[r][k]; t1[k] = o[r][k + 4]; }
        f32x4* dst = reinterpret_cast<f32x4*>(out + (size_t)(i0 + r) * J_DIM) + 2 * c8;
        dst[0] = t0;   // cached stores: full-line write-combining in L2
        dst[1] = t1;
    }
}

extern "C" void kernel_launch(void* const* d_in, const int* in_sizes, int n_in,
                              void* d_out, int out_size, void* d_ws, size_t ws_size,
                              hipStream_t stream) {
    const float* weight = (const float*)d_in[0];
    const float* smask  = (const float*)d_in[1];
    const float* ps0    = (const float*)d_in[2];
    const float* ps1    = (const float*)d_in[3];
    const int*   perm0  = (const int*)d_in[4];
    const int*   perm1  = (const int*)d_in[5];
    float* out = (float*)d_out;
    unsigned short* swb = (unsigned short*)d_ws;  // I*J*2 = 32 MiB scratch

    const int n8 = I_DIM * J_DIM / 8;
    sw_kernel<<<n8 / 256, 256, 0, stream>>>(weight, smask, swb, n8);
    fused_kernel<<<I_DIM / RROWS, FUSED_THREADS, 0, stream>>>(
        swb, ps0, ps1, perm0, perm1, out);
}

// Round 9
// 92.281 us; speedup vs baseline: 2.9128x; 2.9128x over previous
//
#include <hip/hip_runtime.h>
#include <hip/hip_bf16.h>

#define I_DIM 4096
#define J_DIM 4096
#define NPERM0 10
#define NPERM1 10
#define RROWS 4            // output rows per block (K2)
#define CHUNKS 8           // column chunks == XCD count
#define CCOLS (J_DIM / CHUNKS)   // 512 columns per chunk
#define K1_ROWS 16         // v rows per K1 block (4 waves x 4 rows)

typedef float          f32x4 __attribute__((ext_vector_type(4)));
typedef int            i32x4 __attribute__((ext_vector_type(4)));
typedef unsigned short u16x4 __attribute__((ext_vector_type(4)));
typedef unsigned short u16x8 __attribute__((ext_vector_type(8)));

// XOR-swizzle for 8-byte LDS slots: physical = s ^ ((s>>4)&7). Bijective.
// Transpose writes (s = 8*c8+k, fixed k): 16 consecutive lanes hit 16
// distinct low-4 slots -> all 32 banks exactly 4x per wave (b64 optimum).
__device__ __forceinline__ int swzB(int s) { return s ^ ((s >> 4) & 7); }

__device__ __forceinline__ float bf2f(unsigned short u) {
    return __uint_as_float((unsigned)u << 16);
}
__device__ __forceinline__ unsigned short f2bf(float f) {
    unsigned u = __float_as_uint(f);
    u += 0x7FFFu + ((u >> 16) & 1u);
    return (unsigned short)(u >> 16);
}

// soft mask: clip((xi-gamma)*sigmoid(x)+gamma, 0, 1), xi=1.1, gamma=-0.1
__device__ __forceinline__ float soft_mask(float x) {
    float s = 1.0f / (1.0f + __expf(-x));
    return fminf(fmaxf(1.2f * s - 0.1f, 0.0f), 1.0f);
}

// Pass 0: sw = bf16(weight * soft_mask(sparse_mask)). Streaming, 160 MB.
__global__ __launch_bounds__(256) void sw_kernel(
    const float* __restrict__ w, const float* __restrict__ m,
    unsigned short* __restrict__ swb, int n8) {
    int idx = blockIdx.x * blockDim.x + threadIdx.x;
    if (idx >= n8) return;
    const f32x4* w4 = reinterpret_cast<const f32x4*>(w) + 2 * (size_t)idx;
    const f32x4* m4 = reinterpret_cast<const f32x4*>(m) + 2 * (size_t)idx;
    f32x4 w0 = __builtin_nontemporal_load(w4);
    f32x4 w1 = __builtin_nontemporal_load(w4 + 1);
    f32x4 m0 = __builtin_nontemporal_load(m4);
    f32x4 m1 = __builtin_nontemporal_load(m4 + 1);
    u16x8 o;
#pragma unroll
    for (int k = 0; k < 4; ++k) {
        o[k]     = f2bf(w0[k] * soft_mask(m0[k]));
        o[k + 4] = f2bf(w1[k] * soft_mask(m1[k]));
    }
    reinterpret_cast<u16x8*>(swb)[idx] = o;
}

// K1 row-mix, column-chunked for per-XCD L2 residency:
//   v[i, jc] = sum_p ps0[p,i] * sw[perm0[p,i], jc],  jc = one 512-col chunk.
// chunk = blockIdx % 8: HW round-robin puts all blocks of chunk c on XCD c,
// whose 4 MiB L2 exactly holds that 4096-row x 1KB column slice of sw ->
// the random row gathers become L2 hits after first touch.
// Each wave owns 4 v-rows x 512 cols (lane = column octet); round-6-style
// unroll-2 loop (proven no-spill).
__global__ __launch_bounds__(256) void rowmix_kernel(
    const unsigned short* __restrict__ swb,   // (I, J) bf16
    const float* __restrict__ ps0,            // (NPERM0, I)
    const int*   __restrict__ perm0,          // (NPERM0, I)
    unsigned short* __restrict__ vb) {        // (I, J) bf16
    const int chunk = blockIdx.x & (CHUNKS - 1);
    const int rg    = blockIdx.x / CHUNKS;
    const int wave  = threadIdx.x >> 6;
    const int lane  = threadIdx.x & 63;
    const int i0    = rg * K1_ROWS + wave * 4;           // 4 rows per wave
    const size_t colbase = (size_t)chunk * CCOLS + (size_t)lane * 8;

    float acc[4][8];
#pragma unroll
    for (int r = 0; r < 4; ++r)
#pragma unroll
        for (int k = 0; k < 8; ++k) acc[r][k] = 0.f;

#pragma unroll 2
    for (int p = 0; p < NPERM0; ++p) {
        u16x8 vv[4];
#pragma unroll
        for (int r = 0; r < 4; ++r) {
            int row = perm0[p * I_DIM + i0 + r];          // wave-uniform
            vv[r] = *reinterpret_cast<const u16x8*>(
                        swb + (size_t)row * J_DIM + colbase);
        }
#pragma unroll
        for (int r = 0; r < 4; ++r) {
            float s = ps0[p * I_DIM + i0 + r];            // wave-uniform
#pragma unroll
            for (int k = 0; k < 8; ++k) acc[r][k] += s * bf2f(vv[r][k]);
        }
    }
#pragma unroll
    for (int r = 0; r < 4; ++r) {
        u16x8 o;
#pragma unroll
        for (int k = 0; k < 8; ++k) o[k] = f2bf(acc[r][k]);
        *reinterpret_cast<u16x8*>(vb + (size_t)(i0 + r) * J_DIM + colbase) = o;
    }
}

// K2 col-mix, fully streaming:
//   out[i_r, c] = sum_q v[i_r, perm1[q,c]] * ps1[q,c]
// Block owns 4 full v rows: sequential bf16 loads -> LDS transpose
// ([c] -> u16x4 of 4 rows, swizzled) -> round-7 phase-B gather (clean,
// VGPR 32, no spill) -> cached f32 stores.
__global__ __launch_bounds__(512, 4) void colmix_kernel(
    const unsigned short* __restrict__ vb,    // (I, J) bf16
    const float* __restrict__ ps1,            // (NPERM1, J)
    const int*   __restrict__ perm1,          // (NPERM1, J)
    float* __restrict__ out) {
    __shared__ u16x4 vlds[J_DIM];             // 32 KiB

    const int i0 = blockIdx.x * RROWS;
    const int c8 = threadIdx.x;               // column octet, 0..511

    // Load 4 rows (sequential) and transpose into LDS.
    u16x8 rowv[RROWS];
#pragma unroll
    for (int r = 0; r < RROWS; ++r)
        rowv[r] = *reinterpret_cast<const u16x8*>(
                      vb + (size_t)(i0 + r) * J_DIM + (size_t)c8 * 8);
#pragma unroll
    for (int k = 0; k < 8; ++k) {
        u16x4 t;
#pragma unroll
        for (int r = 0; r < RROWS; ++r) t[r] = rowv[r][k];
        vlds[swzB(8 * c8 + k)] = t;
    }
    __syncthreads();

    float o[RROWS][8];
#pragma unroll
    for (int r = 0; r < RROWS; ++r)
#pragma unroll
        for (int k = 0; k < 8; ++k) o[r][k] = 0.f;

#pragma unroll 2
    for (int q = 0; q < NPERM1; ++q) {
        const i32x4* pq = reinterpret_cast<const i32x4*>(perm1 + (size_t)q * J_DIM);
        const f32x4* sq = reinterpret_cast<const f32x4*>(ps1  + (size_t)q * J_DIM);
        i32x4 pc0 = pq[2 * c8];
        i32x4 pc1 = pq[2 * c8 + 1];
        f32x4 s0  = sq[2 * c8];
        f32x4 s1  = sq[2 * c8 + 1];
        u16x4 g[8];
#pragma unroll
        for (int k = 0; k < 4; ++k) {
            g[k]     = vlds[swzB(pc0[k])];
            g[k + 4] = vlds[swzB(pc1[k])];
        }
#pragma unroll
        for (int k = 0; k < 4; ++k) {
#pragma unroll
            for (int r = 0; r < RROWS; ++r) {
                o[r][k]     += s0[k] * bf2f(g[k][r]);
                o[r][k + 4] += s1[k] * bf2f(g[k + 4][r]);
            }
        }
    }
#pragma unroll
    for (int r = 0; r < RROWS; ++r) {
        f32x4 t0, t1;
#pragma unroll
        for (int k = 0; k < 4; ++k) { t0[k] = o[r][k]; t1[k] = o[r][k + 4]; }
        f32x4* dst = reinterpret_cast<f32x4*>(out + (size_t)(i0 + r) * J_DIM) + 2 * c8;
        dst[0] = t0;   // cached: L2 write-combines full lines
        dst[1] = t1;
    }
}

extern "C" void kernel_launch(void* const* d_in, const int* in_sizes, int n_in,
                              void* d_out, int out_size, void* d_ws, size_t ws_size,
                              hipStream_t stream) {
    const float* weight = (const float*)d_in[0];
    const float* smask  = (const float*)d_in[1];
    const float* ps0    = (const float*)d_in[2];
    const float* ps1    = (const float*)d_in[3];
    const int*   perm0  = (const int*)d_in[4];
    const int*   perm1  = (const int*)d_in[5];
    float* out = (float*)d_out;

    unsigned short* swb = (unsigned short*)d_ws;                       // 32 MiB
    unsigned short* vb  = swb + (size_t)I_DIM * J_DIM;                 // 32 MiB

    const int n8 = I_DIM * J_DIM / 8;
    sw_kernel<<<n8 / 256, 256, 0, stream>>>(weight, smask, swb, n8);
    rowmix_kernel<<<CHUNKS * (I_DIM / K1_ROWS), 256, 0, stream>>>(
        swb, ps0, perm0, vb);
    colmix_kernel<<<I_DIM / RROWS, 512, 0, stream>>>(vb, ps1, perm1, out);
}

// Round 10
// 90.451 us; speedup vs baseline: 2.9717x; 1.0202x over previous
//
#include <hip/hip_runtime.h>
#include <hip/hip_bf16.h>

#define I_DIM 4096
#define J_DIM 4096
#define NPERM0 10
#define NPERM1 10
#define RROWS 4            // output rows per block (K2)
#define CHUNKS 8           // column chunks == XCD count
#define CCOLS (J_DIM / CHUNKS)   // 512 columns per chunk (4 MiB bf16 slice)
#define K1_ROWS 16         // v rows per K1 block (4 waves x 4 rows)

typedef float          f32x4 __attribute__((ext_vector_type(4)));
typedef int            i32x4 __attribute__((ext_vector_type(4)));
typedef unsigned short u16x4 __attribute__((ext_vector_type(4)));
typedef unsigned short u16x8 __attribute__((ext_vector_type(8)));

// XOR-swizzle for 8-byte LDS slots: physical = s ^ ((s>>4)&7). Bijective.
// Transpose writes (s = 8*c8+k, fixed k): 16 consecutive lanes hit 16
// distinct low-4 slots -> all 32 banks exactly 4x per wave (b64 optimum).
__device__ __forceinline__ int swzB(int s) { return s ^ ((s >> 4) & 7); }

__device__ __forceinline__ float bf2f(unsigned short u) {
    return __uint_as_float((unsigned)u << 16);
}
__device__ __forceinline__ unsigned short f2bf(float f) {
    unsigned u = __float_as_uint(f);
    u += 0x7FFFu + ((u >> 16) & 1u);
    return (unsigned short)(u >> 16);
}

// soft mask: clip((xi-gamma)*sigmoid(x)+gamma, 0, 1), xi=1.1, gamma=-0.1
__device__ __forceinline__ float soft_mask(float x) {
    float s = 1.0f / (1.0f + __expf(-x));
    return fminf(fmaxf(1.2f * s - 0.1f, 0.0f), 1.0f);
}

// Pass 0: sw = bf16(weight * soft_mask(sparse_mask)). Streaming, 160 MB.
// Cached store: sw should land in L3 (256 MB) for K1's first touch.
__global__ __launch_bounds__(256) void sw_kernel(
    const float* __restrict__ w, const float* __restrict__ m,
    unsigned short* __restrict__ swb, int n8) {
    int idx = blockIdx.x * blockDim.x + threadIdx.x;
    if (idx >= n8) return;
    const f32x4* w4 = reinterpret_cast<const f32x4*>(w) + 2 * (size_t)idx;
    const f32x4* m4 = reinterpret_cast<const f32x4*>(m) + 2 * (size_t)idx;
    f32x4 w0 = __builtin_nontemporal_load(w4);
    f32x4 w1 = __builtin_nontemporal_load(w4 + 1);
    f32x4 m0 = __builtin_nontemporal_load(m4);
    f32x4 m1 = __builtin_nontemporal_load(m4 + 1);
    u16x8 o;
#pragma unroll
    for (int k = 0; k < 4; ++k) {
        o[k]     = f2bf(w0[k] * soft_mask(m0[k]));
        o[k + 4] = f2bf(w1[k] * soft_mask(m1[k]));
    }
    reinterpret_cast<u16x8*>(swb)[idx] = o;
}

// K1 row-mix, column-chunked for per-XCD L2 residency:
//   v[i, jc] = sum_p ps0[p,i] * sw[perm0[p,i], jc],  jc = one 512-col chunk.
// chunk = blockIdx % 8: HW round-robin puts chunk c's blocks on XCD c whose
// 4 MiB L2 holds that column slice of sw. ROUND-9 FIX: vb stores are
// NON-TEMPORAL so the 4 MiB of write-once output doesn't evict the sw
// gather working set from L2 (round 9: chunking bought nothing because
// stores thrashed the exactly-L2-sized slice).
__global__ __launch_bounds__(256, 4) void rowmix_kernel(
    const unsigned short* __restrict__ swb,   // (I, J) bf16
    const float* __restrict__ ps0,            // (NPERM0, I)
    const int*   __restrict__ perm0,          // (NPERM0, I)
    unsigned short* __restrict__ vb) {        // (I, J) bf16
    const int chunk = blockIdx.x & (CHUNKS - 1);
    const int rg    = blockIdx.x / CHUNKS;
    const int wave  = threadIdx.x >> 6;
    const int lane  = threadIdx.x & 63;
    const int i0    = rg * K1_ROWS + wave * 4;           // 4 rows per wave
    const size_t colbase = (size_t)chunk * CCOLS + (size_t)lane * 8;

    float acc[4][8];
#pragma unroll
    for (int r = 0; r < 4; ++r)
#pragma unroll
        for (int k = 0; k < 8; ++k) acc[r][k] = 0.f;

#pragma unroll 2
    for (int p = 0; p < NPERM0; ++p) {
        u16x8 vv[4];
#pragma unroll
        for (int r = 0; r < 4; ++r) {
            int row = perm0[p * I_DIM + i0 + r];          // wave-uniform
            vv[r] = *reinterpret_cast<const u16x8*>(
                        swb + (size_t)row * J_DIM + colbase);
        }
#pragma unroll
        for (int r = 0; r < 4; ++r) {
            float s = ps0[p * I_DIM + i0 + r];            // wave-uniform
#pragma unroll
            for (int k = 0; k < 8; ++k) acc[r][k] += s * bf2f(vv[r][k]);
        }
    }
#pragma unroll
    for (int r = 0; r < 4; ++r) {
        u16x8 o;
#pragma unroll
        for (int k = 0; k < 8; ++k) o[k] = f2bf(acc[r][k]);
        __builtin_nontemporal_store(
            o, reinterpret_cast<u16x8*>(vb + (size_t)(i0 + r) * J_DIM + colbase));
    }
}

// K2 col-mix, fully streaming:
//   out[i_r, c] = sum_q v[i_r, perm1[q,c]] * ps1[q,c]
// Block owns 4 full v rows: sequential NT bf16 loads (read-once) -> LDS
// transpose ([c] -> u16x4, swizzled) -> LDS gathers -> cached f32 stores.
__global__ __launch_bounds__(512, 4) void colmix_kernel(
    const unsigned short* __restrict__ vb,    // (I, J) bf16
    const float* __restrict__ ps1,            // (NPERM1, J)
    const int*   __restrict__ perm1,          // (NPERM1, J)
    float* __restrict__ out) {
    __shared__ u16x4 vlds[J_DIM];             // 32 KiB

    const int i0 = blockIdx.x * RROWS;
    const int c8 = threadIdx.x;               // column octet, 0..511

    // Load 4 rows (sequential, read-once -> NT) and transpose into LDS.
    u16x8 rowv[RROWS];
#pragma unroll
    for (int r = 0; r < RROWS; ++r)
        rowv[r] = __builtin_nontemporal_load(
                      reinterpret_cast<const u16x8*>(
                          vb + (size_t)(i0 + r) * J_DIM + (size_t)c8 * 8));
#pragma unroll
    for (int k = 0; k < 8; ++k) {
        u16x4 t;
#pragma unroll
        for (int r = 0; r < RROWS; ++r) t[r] = rowv[r][k];
        vlds[swzB(8 * c8 + k)] = t;
    }
    __syncthreads();

    float o[RROWS][8];
#pragma unroll
    for (int r = 0; r < RROWS; ++r)
#pragma unroll
        for (int k = 0; k < 8; ++k) o[r][k] = 0.f;

#pragma unroll 2
    for (int q = 0; q < NPERM1; ++q) {
        const i32x4* pq = reinterpret_cast<const i32x4*>(perm1 + (size_t)q * J_DIM);
        const f32x4* sq = reinterpret_cast<const f32x4*>(ps1  + (size_t)q * J_DIM);
        i32x4 pc0 = pq[2 * c8];
        i32x4 pc1 = pq[2 * c8 + 1];
        f32x4 s0  = sq[2 * c8];
        f32x4 s1  = sq[2 * c8 + 1];
        u16x4 g[8];
#pragma unroll
        for (int k = 0; k < 4; ++k) {
            g[k]     = vlds[swzB(pc0[k])];
            g[k + 4] = vlds[swzB(pc1[k])];
        }
#pragma unroll
        for (int k = 0; k < 4; ++k) {
#pragma unroll
            for (int r = 0; r < RROWS; ++r) {
                o[r][k]     += s0[k] * bf2f(g[k][r]);
                o[r][k + 4] += s1[k] * bf2f(g[k + 4][r]);
            }
        }
    }
#pragma unroll
    for (int r = 0; r < RROWS; ++r) {
        f32x4 t0, t1;
#pragma unroll
        for (int k = 0; k < 4; ++k) { t0[k] = o[r][k]; t1[k] = o[r][k + 4]; }
        f32x4* dst = reinterpret_cast<f32x4*>(out + (size_t)(i0 + r) * J_DIM) + 2 * c8;
        dst[0] = t0;   // cached: L2 write-combines full lines
        dst[1] = t1;
    }
}

extern "C" void kernel_launch(void* const* d_in, const int* in_sizes, int n_in,
                              void* d_out, int out_size, void* d_ws, size_t ws_size,
                              hipStream_t stream) {
    const float* weight = (const float*)d_in[0];
    const float* smask  = (const float*)d_in[1];
    const float* ps0    = (const float*)d_in[2];
    const float* ps1    = (const float*)d_in[3];
    const int*   perm0  = (const int*)d_in[4];
    const int*   perm1  = (const int*)d_in[5];
    float* out = (float*)d_out;

    unsigned short* swb = (unsigned short*)d_ws;                       // 32 MiB
    unsigned short* vb  = swb + (size_t)I_DIM * J_DIM;                 // 32 MiB

    const int n8 = I_DIM * J_DIM / 8;
    sw_kernel<<<n8 / 256, 256, 0, stream>>>(weight, smask, swb, n8);
    rowmix_kernel<<<CHUNKS * (I_DIM / K1_ROWS), 256, 0, stream>>>(
        swb, ps0, perm0, vb);
    colmix_kernel<<<I_DIM / RROWS, 512, 0, stream>>>(vb, ps1, perm1, out);
}

// Round 11
// 78.971 us; speedup vs baseline: 3.4037x; 1.1454x over previous
//
#include <hip/hip_runtime.h>
#include <hip/hip_bf16.h>

#define I_DIM 4096
#define J_DIM 4096
#define NPERM0 10
#define NPERM1 10
#define RROWS 4            // rows per K1' block
#define CHUNKS 8           // column chunks == XCD count
#define CCOLS (J_DIM / CHUNKS)   // 512 cols per chunk (4 MiB bf16 slice)
#define K2_ROWS 16         // out rows per K2' block (4 waves x 4 rows)

typedef float          f32x4 __attribute__((ext_vector_type(4)));
typedef int            i32x4 __attribute__((ext_vector_type(4)));
typedef unsigned short u16x4 __attribute__((ext_vector_type(4)));
typedef unsigned short u16x8 __attribute__((ext_vector_type(8)));

// XOR-swizzle for 8-byte LDS slots: physical = s ^ ((s>>4)&7). Bijective.
// Transpose writes (s = 8*c8+k, fixed k): 16 consecutive lanes hit 16
// distinct low-4 slots -> all 32 banks exactly 4x per wave (b64 optimum).
__device__ __forceinline__ int swzB(int s) { return s ^ ((s >> 4) & 7); }

__device__ __forceinline__ float bf2f(unsigned short u) {
    return __uint_as_float((unsigned)u << 16);
}
__device__ __forceinline__ unsigned short f2bf(float f) {
    unsigned u = __float_as_uint(f);
    u += 0x7FFFu + ((u >> 16) & 1u);
    return (unsigned short)(u >> 16);
}

// soft mask: clip((xi-gamma)*sigmoid(x)+gamma, 0, 1), xi=1.1, gamma=-0.1
__device__ __forceinline__ float soft_mask(float x) {
    float s = 1.0f / (1.0f + __expf(-x));
    return fminf(fmaxf(1.2f * s - 0.1f, 0.0f), 1.0f);
}

// K1': fused soft-mask + COLUMN-mix (reference order!):
//   u[i,c] = sum_q ps1[q,c] * sw[i, perm1[q,c]],  sw[i,j] = w[i,j]*mask(m[i,j])
// Block owns 4 rows. weight/mask rows are read SEQUENTIALLY (each element
// exactly once, NT loads), sw computed in-register, transposed into LDS
// ([c] -> u16x4 of 4 rows, swizzled), then the within-row column gather
// runs from LDS. Kills the separate pass-0 and its 32 MB sw round-trip.
__global__ __launch_bounds__(512, 4) void maskcolmix_kernel(
    const float* __restrict__ w,              // (I, J) f32
    const float* __restrict__ m,              // (I, J) f32
    const float* __restrict__ ps1,            // (NPERM1, J)
    const int*   __restrict__ perm1,          // (NPERM1, J)
    unsigned short* __restrict__ ub) {        // (I, J) bf16 out
    __shared__ u16x4 vlds[J_DIM];             // 32 KiB

    const int i0 = blockIdx.x * RROWS;
    const int c8 = threadIdx.x;               // column octet, 0..511

    // Load w,m (8 cols x 4 rows), compute sw bf16 in-register.
    u16x8 rowv[RROWS];
#pragma unroll
    for (int r = 0; r < RROWS; ++r) {
        const f32x4* w4 = reinterpret_cast<const f32x4*>(
                              w + (size_t)(i0 + r) * J_DIM) + 2 * c8;
        const f32x4* m4 = reinterpret_cast<const f32x4*>(
                              m + (size_t)(i0 + r) * J_DIM) + 2 * c8;
        f32x4 w0 = __builtin_nontemporal_load(w4);
        f32x4 w1 = __builtin_nontemporal_load(w4 + 1);
        f32x4 m0 = __builtin_nontemporal_load(m4);
        f32x4 m1 = __builtin_nontemporal_load(m4 + 1);
        u16x8 o;
#pragma unroll
        for (int k = 0; k < 4; ++k) {
            o[k]     = f2bf(w0[k] * soft_mask(m0[k]));
            o[k + 4] = f2bf(w1[k] * soft_mask(m1[k]));
        }
        rowv[r] = o;
    }
    // Transpose into LDS (swizzled, conflict-free b64).
#pragma unroll
    for (int k = 0; k < 8; ++k) {
        u16x4 t;
#pragma unroll
        for (int r = 0; r < RROWS; ++r) t[r] = rowv[r][k];
        vlds[swzB(8 * c8 + k)] = t;
    }
    __syncthreads();

    // Column gather + combine (proven round-7/9 shape).
    float o[RROWS][8];
#pragma unroll
    for (int r = 0; r < RROWS; ++r)
#pragma unroll
        for (int k = 0; k < 8; ++k) o[r][k] = 0.f;

#pragma unroll 2
    for (int q = 0; q < NPERM1; ++q) {
        const i32x4* pq = reinterpret_cast<const i32x4*>(perm1 + (size_t)q * J_DIM);
        const f32x4* sq = reinterpret_cast<const f32x4*>(ps1  + (size_t)q * J_DIM);
        i32x4 pc0 = pq[2 * c8];
        i32x4 pc1 = pq[2 * c8 + 1];
        f32x4 s0  = sq[2 * c8];
        f32x4 s1  = sq[2 * c8 + 1];
        u16x4 g[8];
#pragma unroll
        for (int k = 0; k < 4; ++k) {
            g[k]     = vlds[swzB(pc0[k])];
            g[k + 4] = vlds[swzB(pc1[k])];
        }
#pragma unroll
        for (int k = 0; k < 4; ++k) {
#pragma unroll
            for (int r = 0; r < RROWS; ++r) {
                o[r][k]     += s0[k] * bf2f(g[k][r]);
                o[r][k + 4] += s1[k] * bf2f(g[k + 4][r]);
            }
        }
    }
    // Emit u as bf16 (cached: read by K2' soon, let it live in L2/L3).
#pragma unroll
    for (int r = 0; r < RROWS; ++r) {
        u16x8 ob;
#pragma unroll
        for (int k = 0; k < 8; ++k) ob[k] = f2bf(o[r][k]);
        *reinterpret_cast<u16x8*>(ub + (size_t)(i0 + r) * J_DIM + (size_t)c8 * 8) = ob;
    }
}

// K2': ROW-mix on u -> final out (f32):
//   out[i,c] = sum_p ps0[p,i] * u[perm0[p,i], c]
// Column-chunked (chunk = bid % 8 -> XCD) so each XCD gathers from a 4 MiB
// u slice that fits its L2. Out stores are NT (write-once, keep L2 clean
// for the gather working set). Round-6 proven no-spill loop shape.
__global__ __launch_bounds__(256, 4) void rowmix_out_kernel(
    const unsigned short* __restrict__ ub,    // (I, J) bf16
    const float* __restrict__ ps0,            // (NPERM0, I)
    const int*   __restrict__ perm0,          // (NPERM0, I)
    float* __restrict__ out) {                // (I, J) f32
    const int chunk = blockIdx.x & (CHUNKS - 1);
    const int rg    = blockIdx.x / CHUNKS;
    const int wave  = threadIdx.x >> 6;
    const int lane  = threadIdx.x & 63;
    const int i0    = rg * K2_ROWS + wave * 4;           // 4 rows per wave
    const size_t colbase = (size_t)chunk * CCOLS + (size_t)lane * 8;

    float acc[4][8];
#pragma unroll
    for (int r = 0; r < 4; ++r)
#pragma unroll
        for (int k = 0; k < 8; ++k) acc[r][k] = 0.f;

#pragma unroll 2
    for (int p = 0; p < NPERM0; ++p) {
        u16x8 vv[4];
#pragma unroll
        for (int r = 0; r < 4; ++r) {
            int row = perm0[p * I_DIM + i0 + r];          // wave-uniform
            vv[r] = *reinterpret_cast<const u16x8*>(
                        ub + (size_t)row * J_DIM + colbase);
        }
#pragma unroll
        for (int r = 0; r < 4; ++r) {
            float s = ps0[p * I_DIM + i0 + r];            // wave-uniform
#pragma unroll
            for (int k = 0; k < 8; ++k) acc[r][k] += s * bf2f(vv[r][k]);
        }
    }
#pragma unroll
    for (int r = 0; r < 4; ++r) {
        f32x4 t0, t1;
#pragma unroll
        for (int k = 0; k < 4; ++k) { t0[k] = acc[r][k]; t1[k] = acc[r][k + 4]; }
        float* dst = out + (size_t)(i0 + r) * J_DIM + colbase;
        __builtin_nontemporal_store(t0, reinterpret_cast<f32x4*>(dst));
        __builtin_nontemporal_store(t1, reinterpret_cast<f32x4*>(dst) + 1);
    }
}

extern "C" void kernel_launch(void* const* d_in, const int* in_sizes, int n_in,
                              void* d_out, int out_size, void* d_ws, size_t ws_size,
                              hipStream_t stream) {
    const float* weight = (const float*)d_in[0];
    const float* smask  = (const float*)d_in[1];
    const float* ps0    = (const float*)d_in[2];
    const float* ps1    = (const float*)d_in[3];
    const int*   perm0  = (const int*)d_in[4];
    const int*   perm1  = (const int*)d_in[5];
    float* out = (float*)d_out;

    unsigned short* ub = (unsigned short*)d_ws;   // 32 MiB intermediate u

    maskcolmix_kernel<<<I_DIM / RROWS, 512, 0, stream>>>(
        weight, smask, ps1, perm1, ub);
    rowmix_out_kernel<<<CHUNKS * (I_DIM / K2_ROWS), 256, 0, stream>>>(
        ub, ps0, perm0, out);
}